// Round 12
// baseline (141.906 us; speedup 1.0000x reference)
//
#include <hip/hip_runtime.h>

typedef __bf16 bf16;
typedef __bf16 bf16x8 __attribute__((ext_vector_type(8)));
typedef __bf16 bf16x4 __attribute__((ext_vector_type(4)));
typedef float f32x4 __attribute__((ext_vector_type(4)));
typedef float f32x16 __attribute__((ext_vector_type(16)));

// x: [256][4096] f32, conv_w: [1536][256] f32, out: [512][4096] f32
// heads=8; channels per head: key [0:64), query [64:128), value [128:192)
// qkvT per head (786432): [QT(query) [4096][64] | KT_blk | V_blk]
// KT_blk: per L-tile t (64 l): 8 chunks of 512 elems; chunk (lb*4+ks), lane=(half<<5)|l31:
//   element K[l = t*64 + lb*32 + l31][kd = ks*16 + half*8 + j] at offset
//   t*4096 + (lb*4+ks)*512 + lane*8 + j   -> k_attn frag load = base + lane*16 (coalesced)
// V_blk: same with (kb,ks): V[kd = kb*32+l31][l = t*64 + ks*16 + half*8 + j].
// k_conv stores RAW bf16; k_normqk normalizes Q (with log2(e)/8) and K in place;
// V affine folds into k_final: out = a_v*(sum O)/(sum L) + b_v.

#define QF 0.18033688011112042f   // log2(e)/8
#define EXPF(x) __builtin_amdgcn_exp2f(x)

union U4 { bf16x4 v; unsigned u[2]; };
union U8 { bf16x8 v; unsigned u[4]; };

// ---------------- K_misc: xpose + cast_w + zero(cs) ----------------
__global__ void k_misc(const float* __restrict__ x, const float* __restrict__ w,
                       bf16* __restrict__ xT, bf16* __restrict__ wb, float* __restrict__ cs) {
    int b = blockIdx.x;
    if (b < 512) {
        int t = b * 256 + threadIdx.x;
        int p  = t & 4095;
        int c0 = (t >> 12) * 8;
        bf16x8 o;
#pragma unroll
        for (int j = 0; j < 8; j++) o[j] = (bf16)x[(c0 + j) * 4096 + p];
        *(bf16x8*)(xT + p * 256 + c0) = o;
    } else if (b < 896) {
        int idx = ((b - 512) * 256 + threadIdx.x) * 4;
        float4 f = *(const float4*)(w + idx);
        bf16x4 o;
        o[0] = (bf16)f.x; o[1] = (bf16)f.y; o[2] = (bf16)f.z; o[3] = (bf16)f.w;
        *(bf16x4*)(wb + idx) = o;
    } else {
#pragma unroll
        for (int i = 0; i < 12; i++) cs[i * 256 + threadIdx.x] = 0.f;
    }
}

// ---------------- K1: conv GEMM, LDS-staged; K/V stored in blocked frag order ----------------
__global__ __launch_bounds__(256) void k_conv(const bf16* __restrict__ Wb,
                                              const bf16* __restrict__ xT,
                                              bf16* __restrict__ qkvT,
                                              float* __restrict__ cs) {
    __shared__ __attribute__((aligned(16))) bf16 xs[64 * 72];
    __shared__ __attribute__((aligned(16))) bf16 ws2[64 * 72];
    int wid = threadIdx.x >> 6, lane = threadIdx.x & 63;
    int quad = lane >> 4, l15 = lane & 15;
    int g  = blockIdx.x % 24;
    int pb = (blockIdx.x / 24) * 64;
    int h = g / 3, sec = g % 3;          // 0=key 1=query 2=value
    int ob = g * 64;

    int srow = threadIdx.x >> 2;          // 0..63
    int scol = (threadIdx.x & 3) * 16;    // 0/16/32/48

    f32x4 acc[4];
#pragma unroll
    for (int c = 0; c < 4; c++) acc[c] = (f32x4){0.f, 0.f, 0.f, 0.f};

    bf16x8 fx0 = *(const bf16x8*)(xT + (pb + srow) * 256 + scol);
    bf16x8 fx1 = *(const bf16x8*)(xT + (pb + srow) * 256 + scol + 8);
    bf16x8 fw0 = *(const bf16x8*)(Wb + (ob + srow) * 256 + scol);
    bf16x8 fw1 = *(const bf16x8*)(Wb + (ob + srow) * 256 + scol + 8);

    for (int c4 = 0; c4 < 4; c4++) {
        __syncthreads();
        *(bf16x8*)(xs  + srow * 72 + scol)     = fx0;
        *(bf16x8*)(xs  + srow * 72 + scol + 8) = fx1;
        *(bf16x8*)(ws2 + srow * 72 + scol)     = fw0;
        *(bf16x8*)(ws2 + srow * 72 + scol + 8) = fw1;
        __syncthreads();

        if (c4 < 3) {
            int co = (c4 + 1) * 64;
            fx0 = *(const bf16x8*)(xT + (pb + srow) * 256 + co + scol);
            fx1 = *(const bf16x8*)(xT + (pb + srow) * 256 + co + scol + 8);
            fw0 = *(const bf16x8*)(Wb + (ob + srow) * 256 + co + scol);
            fw1 = *(const bf16x8*)(Wb + (ob + srow) * 256 + co + scol + 8);
        }

#pragma unroll
        for (int k2 = 0; k2 < 2; k2++) {
            bf16x8 a = *(const bf16x8*)(ws2 + (wid * 16 + l15) * 72 + k2 * 32 + quad * 8);
#pragma unroll
            for (int c = 0; c < 4; c++) {
                bf16x8 b = *(const bf16x8*)(xs + (c * 16 + l15) * 72 + k2 * 32 + quad * 8);
                acc[c] = __builtin_amdgcn_mfma_f32_16x16x32_bf16(a, b, acc[c], 0, 0, 0);
            }
        }
    }

    int ch0 = wid * 16 + quad * 4;
#pragma unroll
    for (int r = 0; r < 4; r++) {
        float sp  = acc[0][r] + acc[1][r] + acc[2][r] + acc[3][r];
        float ssp = acc[0][r] * acc[0][r] + acc[1][r] * acc[1][r]
                  + acc[2][r] * acc[2][r] + acc[3][r] * acc[3][r];
#pragma unroll
        for (int m = 1; m < 16; m <<= 1) {
            sp  += __shfl_xor(sp,  m, 64);
            ssp += __shfl_xor(ssp, m, 64);
        }
        if (l15 == 0) {
            atomicAdd(cs + (ob + ch0 + r) * 2,     sp);
            atomicAdd(cs + (ob + ch0 + r) * 2 + 1, ssp);
        }
    }

    __syncthreads();
    bf16* tile = xs;
    if (sec == 2) {                       // V: tile[kd][l], stride 72
#pragma unroll
        for (int c = 0; c < 4; c++)
#pragma unroll
            for (int r = 0; r < 4; r++)
                tile[(ch0 + r) * 72 + c * 16 + l15] = (bf16)acc[c][r];
    } else {                              // Q/K: tile[l or px][ch], stride 72
#pragma unroll
        for (int c = 0; c < 4; c++) {
            bf16x4 o;
#pragma unroll
            for (int r = 0; r < 4; r++) o[r] = (bf16)acc[c][r];
            *(bf16x4*)(&tile[(c * 16 + l15) * 72 + ch0]) = o;
        }
    }
    __syncthreads();
    bf16* base = qkvT + h * 786432;
    int t2 = pb >> 6;                     // this block covers exactly one L-tile
    if (sec == 1) {                       // Q linear [px][64]
#pragma unroll
        for (int it = 0; it < 2; it++) {
            int e = it * 256 + threadIdx.x; int px = e >> 3; int cho = (e & 7) * 8;
            *(bf16x8*)(base + (pb + px) * 64 + cho) = *(const bf16x8*)(&tile[px * 72 + cho]);
        }
    } else {                              // K/V blocked: dest offset = t*4096 + e*8
        bf16* dst = base + (sec == 0 ? 262144 : 524288);
#pragma unroll
        for (int it = 0; it < 2; it++) {
            int e = it * 256 + threadIdx.x;          // e = (b2*4+ks)*64 + half*32 + l31
            int r = (e >> 8) * 32 + (e & 31);        // row in tile (l for K, kd for V)
            int c = ((e >> 6) & 3) * 16 + ((e >> 5) & 1) * 8;
            *(bf16x8*)(dst + t2 * 4096 + e * 8) = *(const bf16x8*)(&tile[r * 72 + c]);
        }
    }
}

// ---------------- K2: in-place affine on Q (linear) / K (blocked) ----------------
__global__ __launch_bounds__(256) void k_normqk(bf16* __restrict__ qkv,
                                                const float2* __restrict__ cs,
                                                const float* __restrict__ gnw,
                                                const float* __restrict__ gnb) {
    int h    = blockIdx.x >> 8;
    int base = (blockIdx.x & 255) * 2048;
    int isQ  = base < 262144;
    int g    = h * 3 + (isQ ? 1 : 0);

    int c = threadIdx.x & 63;
    float2 v = cs[g * 64 + c];
    float s = v.x, ss = v.y;
#pragma unroll
    for (int m = 1; m < 64; m <<= 1) { s += __shfl_xor(s, m, 64); ss += __shfl_xor(ss, m, 64); }
    const float N = 262144.0f;
    float mean = s / N;
    float inv  = rsqrtf(ss / N - mean * mean + 1e-5f);
    float f = isQ ? QF : 1.0f;

    int e = base + threadIdx.x * 8;
    int gc;
    if (isQ) gc = h * 192 + 64 + (e & 63);
    else { int ek = e - 262144; gc = h * 192 + ((ek >> 9) & 3) * 16 + ((ek >> 8) & 1) * 8; }
    bf16* p = qkv + h * 786432 + e;
    bf16x8 vv = *(bf16x8*)p;
    bf16x8 o;
#pragma unroll
    for (int j = 0; j < 8; j++) {
        float gw = gnw[gc + j];
        float a = inv * gw * f;
        float b = (gnb[gc + j] - mean * inv * gw) * f;
        o[j] = (bf16)(a * (float)vv[j] + b);
    }
    *(bf16x8*)p = o;
}

// helper: one 32x32 C-block (S) -> exp2 -> two PV B-fragments (named scalars only)
#define PF_BLOCK(S, PFA, PFB)                                                   \
    {                                                                           \
        float p0 = EXPF(S[0]),  p1 = EXPF(S[1]),  p2 = EXPF(S[2]),  p3 = EXPF(S[3]);   \
        float p4 = EXPF(S[4]),  p5 = EXPF(S[5]),  p6 = EXPF(S[6]),  p7 = EXPF(S[7]);   \
        float p8 = EXPF(S[8]),  p9 = EXPF(S[9]),  p10 = EXPF(S[10]), p11 = EXPF(S[11]); \
        float p12 = EXPF(S[12]), p13 = EXPF(S[13]), p14 = EXPF(S[14]), p15 = EXPF(S[15]); \
        lacc += (((p0 + p1) + (p2 + p3)) + ((p4 + p5) + (p6 + p7)))             \
              + (((p8 + p9) + (p10 + p11)) + ((p12 + p13) + (p14 + p15)));      \
        U4 lo, hi;                                                              \
        lo.v[0] = (bf16)p0;  lo.v[1] = (bf16)p1;  lo.v[2] = (bf16)p2;  lo.v[3] = (bf16)p3;  \
        hi.v[0] = (bf16)p4;  hi.v[1] = (bf16)p5;  hi.v[2] = (bf16)p6;  hi.v[3] = (bf16)p7;  \
        unsigned sa = half ? lo.u[0] : hi.u[0];                                 \
        unsigned sb = half ? lo.u[1] : hi.u[1];                                 \
        unsigned ra = (unsigned)__shfl_xor((int)sa, 32, 64);                    \
        unsigned rb = (unsigned)__shfl_xor((int)sb, 32, 64);                    \
        U8 fA;                                                                  \
        fA.u[0] = half ? ra : lo.u[0];  fA.u[1] = half ? rb : lo.u[1];          \
        fA.u[2] = half ? hi.u[0] : ra;  fA.u[3] = half ? hi.u[1] : rb;          \
        PFA = fA.v;                                                             \
        U4 lo2, hi2;                                                            \
        lo2.v[0] = (bf16)p8;  lo2.v[1] = (bf16)p9;  lo2.v[2] = (bf16)p10; lo2.v[3] = (bf16)p11; \
        hi2.v[0] = (bf16)p12; hi2.v[1] = (bf16)p13; hi2.v[2] = (bf16)p14; hi2.v[3] = (bf16)p15; \
        unsigned sc = half ? lo2.u[0] : hi2.u[0];                               \
        unsigned sd = half ? lo2.u[1] : hi2.u[1];                               \
        unsigned rc = (unsigned)__shfl_xor((int)sc, 32, 64);                    \
        unsigned rd = (unsigned)__shfl_xor((int)sd, 32, 64);                    \
        U8 fB;                                                                  \
        fB.u[0] = half ? rc : lo2.u[0];  fB.u[1] = half ? rd : lo2.u[1];        \
        fB.u[2] = half ? hi2.u[0] : rc;  fB.u[3] = half ? hi2.u[1] : rd;        \
        PFB = fB.v;                                                             \
    }

// ---------------- K3: flash attention, ZERO LDS, blocked frag loads ----------------
// grid 1024 = 8 heads x 32 q-blocks(128q) x 4 L-splits; wave owns 32 q.
__global__ __launch_bounds__(256, 4) void k_attn(const bf16* __restrict__ qkvT,
                                                 bf16* __restrict__ Opart,
                                                 float* __restrict__ Lsum) {
    int bid   = blockIdx.x;
    int h     = bid & 7;                  // XCD L2 affinity
    int qb    = (bid >> 3) & 31;
    int split = bid >> 8;                 // 0..3
    int wid = threadIdx.x >> 6, lane = threadIdx.x & 63;
    int l31 = lane & 31, half = lane >> 5;
    const bf16* QT = qkvT + h * 786432;
    const bf16* KT = QT + 262144;
    const bf16* V  = QT + 524288;
    int qw = qb * 128 + wid * 32;         // wave's 32 q
    int lofs = lane * 8;

    // Q B-fragments (normalized already): B[n=q][k=kd]
    bf16x8 bq[4];
#pragma unroll
    for (int ks = 0; ks < 4; ks++)
        bq[ks] = *(const bf16x8*)(QT + (qw + l31) * 64 + ks * 16 + half * 8);

    f32x16 oacc0 = (f32x16)(0.0f), oacc1 = (f32x16)(0.0f);   // kd 0-31, 32-63
    float ls = 0.f;

    for (int t = split * 16; t < split * 16 + 16; t++) {
        const bf16* Kt = KT + t * 4096 + lofs;
        const bf16* Vt = V  + t * 4096 + lofs;

        // K A-frags: 8 coalesced 16B/lane loads (blocked layout)
        bf16x8 kf[8];
#pragma unroll
        for (int i = 0; i < 8; i++) kf[i] = *(const bf16x8*)(Kt + i * 512);

        // S^T = K·Q : two 32x32 C-tiles (l 0-31 via kf[0..3], 32-63 via kf[4..7])
        f32x16 s0 = (f32x16)(0.0f), s1 = (f32x16)(0.0f);
#pragma unroll
        for (int ks = 0; ks < 4; ks++) {
            s0 = __builtin_amdgcn_mfma_f32_32x32x16_bf16(kf[ks],     bq[ks], s0, 0, 0, 0);
            s1 = __builtin_amdgcn_mfma_f32_32x32x16_bf16(kf[4 + ks], bq[ks], s1, 0, 0, 0);
        }

        // V A-frags issued here: latency hidden under exp2/pack below
        bf16x8 vf[8];
#pragma unroll
        for (int i = 0; i < 8; i++) vf[i] = *(const bf16x8*)(Vt + i * 512);

        float lacc = ls;
        bf16x8 pf0, pf1, pf2, pf3;
        PF_BLOCK(s0, pf0, pf1);           // l 0..31
        PF_BLOCK(s1, pf2, pf3);           // l 32..63
        ls = lacc;

        // O[kd][q] += V·P  (vf[kb*4+ks] pairs with pf[ks])
        oacc0 = __builtin_amdgcn_mfma_f32_32x32x16_bf16(vf[0], pf0, oacc0, 0, 0, 0);
        oacc1 = __builtin_amdgcn_mfma_f32_32x32x16_bf16(vf[4], pf0, oacc1, 0, 0, 0);
        oacc0 = __builtin_amdgcn_mfma_f32_32x32x16_bf16(vf[1], pf1, oacc0, 0, 0, 0);
        oacc1 = __builtin_amdgcn_mfma_f32_32x32x16_bf16(vf[5], pf1, oacc1, 0, 0, 0);
        oacc0 = __builtin_amdgcn_mfma_f32_32x32x16_bf16(vf[2], pf2, oacc0, 0, 0, 0);
        oacc1 = __builtin_amdgcn_mfma_f32_32x32x16_bf16(vf[6], pf2, oacc1, 0, 0, 0);
        oacc0 = __builtin_amdgcn_mfma_f32_32x32x16_bf16(vf[3], pf3, oacc0, 0, 0, 0);
        oacc1 = __builtin_amdgcn_mfma_f32_32x32x16_bf16(vf[7], pf3, oacc1, 0, 0, 0);

        // pacing barrier only (no LDS => no memory-drain semantics needed):
        // keeps the WG's 4 waves on the same tile so L1 serves 3 of 4 re-reads
        __builtin_amdgcn_s_barrier();
    }

    // denominator: halves hold complementary l-rows of col q
    ls += __shfl_xor(ls, 32, 64);
    if (half == 0)
        Lsum[split * 32768 + h * 4096 + qw + l31] = ls;

    // partial O (unnormalized, bf16): row = h*64+kd, col = q
    bf16* Ob = Opart + split * 2097152;
#pragma unroll
    for (int r = 0; r < 16; r++) {
        int kd = (r & 3) + 8 * (r >> 2) + 4 * half;
        Ob[(h * 64 + kd) * 4096 + qw + l31]        = (bf16)oacc0[r];
        Ob[(h * 64 + 32 + kd) * 4096 + qw + l31]   = (bf16)oacc1[r];
    }
}

// ---------------- K4: combine 4 splits + V affine (stats inline) + normalize ----------------
__global__ void k_final(const bf16* __restrict__ Opart, const float* __restrict__ Lsum,
                        const float2* __restrict__ cs, const float* __restrict__ gnw,
                        const float* __restrict__ gnb, float* __restrict__ out) {
    int gid = blockIdx.x * 256 + threadIdx.x;    // 262144
    int row = gid >> 9;
    int c8  = (gid & 511) << 3;
    int h   = row >> 6;

    int g = h * 3 + 2;
    int c = threadIdx.x & 63;
    float2 v = cs[g * 64 + c];
    float s = v.x, ss = v.y;
#pragma unroll
    for (int m = 1; m < 64; m <<= 1) { s += __shfl_xor(s, m, 64); ss += __shfl_xor(ss, m, 64); }
    const float N = 262144.0f;
    float mean = s / N;
    float inv  = rsqrtf(ss / N - mean * mean + 1e-5f);
    int gi = h * 192 + 128 + (row & 63);
    float gw = gnw[gi];
    float va = inv * gw;
    float vb = gnb[gi] - mean * inv * gw;

    float o[8] = {0, 0, 0, 0, 0, 0, 0, 0};
    float l[8] = {0, 0, 0, 0, 0, 0, 0, 0};
#pragma unroll
    for (int sp = 0; sp < 4; sp++) {
        bf16x8 vv = *(const bf16x8*)(Opart + sp * 2097152 + row * 4096 + c8);
        const float* L = Lsum + sp * 32768 + h * 4096 + c8;
        float4 l0 = *(const float4*)L;
        float4 l1 = *(const float4*)(L + 4);
#pragma unroll
        for (int j = 0; j < 8; j++) o[j] += (float)vv[j];
        l[0] += l0.x; l[1] += l0.y; l[2] += l0.z; l[3] += l0.w;
        l[4] += l1.x; l[5] += l1.y; l[6] += l1.z; l[7] += l1.w;
    }
    float4 r0, r1;
    r0.x = va * o[0] / l[0] + vb; r0.y = va * o[1] / l[1] + vb;
    r0.z = va * o[2] / l[2] + vb; r0.w = va * o[3] / l[3] + vb;
    r1.x = va * o[4] / l[4] + vb; r1.y = va * o[5] / l[5] + vb;
    r1.z = va * o[6] / l[6] + vb; r1.w = va * o[7] / l[7] + vb;
    *(float4*)(out + row * 4096 + c8)     = r0;
    *(float4*)(out + row * 4096 + c8 + 4) = r1;
}

extern "C" void kernel_launch(void* const* d_in, const int* in_sizes, int n_in,
                              void* d_out, int out_size, void* d_ws, size_t ws_size,
                              hipStream_t stream) {
    const float* x      = (const float*)d_in[0];
    const float* conv_w = (const float*)d_in[1];
    const float* gn_w   = (const float*)d_in[2];
    const float* gn_b   = (const float*)d_in[3];
    float* out = (float*)d_out;
    char* ws = (char*)d_ws;

    // qkvT [0,12582912); Opart 4x4MB [12582912,29360128); Wb/xT alias Opart
    // (dead after k_conv; Opart first written by k_attn).
    bf16*   qkvT  = (bf16*) (ws);
    bf16*   Opart = (bf16*) (ws + 12582912);
    bf16*   Wb    = (bf16*) (ws + 12582912);
    bf16*   xT    = (bf16*) (ws + 13369344);
    float*  Lsum  = (float*)(ws + 29360128);        // 4*131072 B
    float*  cs    = (float*)(ws + 29884416);        // 12288 B

    hipLaunchKernelGGL(k_misc,   dim3(897),  dim3(256), 0, stream, x, conv_w, xT, Wb, cs);
    hipLaunchKernelGGL(k_conv,   dim3(1536), dim3(256), 0, stream, Wb, xT, qkvT, cs);
    hipLaunchKernelGGL(k_normqk, dim3(2048), dim3(256), 0, stream, qkvT, (const float2*)cs, gn_w, gn_b);
    hipLaunchKernelGGL(k_attn,   dim3(1024), dim3(256), 0, stream, qkvT, Opart, Lsum);
    hipLaunchKernelGGL(k_final,  dim3(1024), dim3(256), 0, stream, Opart, Lsum, (const float2*)cs, gn_w, gn_b, out);
}

// Round 13
// 141.104 us; speedup vs baseline: 1.0057x; 1.0057x over previous
//
#include <hip/hip_runtime.h>

typedef __bf16 bf16;
typedef __bf16 bf16x8 __attribute__((ext_vector_type(8)));
typedef __bf16 bf16x4 __attribute__((ext_vector_type(4)));
typedef float f32x4 __attribute__((ext_vector_type(4)));
typedef float f32x16 __attribute__((ext_vector_type(16)));

// x: [256][4096] f32, conv_w: [1536][256] f32, out: [512][4096] f32
// heads=8; channels per head: key [0:64), query [64:128), value [128:192)
// qkvT per head (786432): [QT(query) [4096][64] | KT_blk | V_blk]  (blocked frag order,
// see R12 comment). k_conv stores RAW bf16; k_normqk normalizes Q (log2(e)/8) and K
// in place; V affine folds into k_final: out = a_v*(sum O)/(sum L) + b_v.

#define QF 0.18033688011112042f   // log2(e)/8
#define EXPF(x) __builtin_amdgcn_exp2f(x)

union U4 { bf16x4 v; unsigned u[2]; };
union U8 { bf16x8 v; unsigned u[4]; };

// ---------------- K_misc: xpose + cast_w + zero(cs) ----------------
__global__ void k_misc(const float* __restrict__ x, const float* __restrict__ w,
                       bf16* __restrict__ xT, bf16* __restrict__ wb, float* __restrict__ cs) {
    int b = blockIdx.x;
    if (b < 512) {
        int t = b * 256 + threadIdx.x;
        int p  = t & 4095;
        int c0 = (t >> 12) * 8;
        bf16x8 o;
#pragma unroll
        for (int j = 0; j < 8; j++) o[j] = (bf16)x[(c0 + j) * 4096 + p];
        *(bf16x8*)(xT + p * 256 + c0) = o;
    } else if (b < 896) {
        int idx = ((b - 512) * 256 + threadIdx.x) * 4;
        float4 f = *(const float4*)(w + idx);
        bf16x4 o;
        o[0] = (bf16)f.x; o[1] = (bf16)f.y; o[2] = (bf16)f.z; o[3] = (bf16)f.w;
        *(bf16x4*)(wb + idx) = o;
    } else {
#pragma unroll
        for (int i = 0; i < 12; i++) cs[i * 256 + threadIdx.x] = 0.f;
    }
}

// ---------------- K1: conv GEMM, LDS-staged; K/V stored in blocked frag order ----------------
__global__ __launch_bounds__(256) void k_conv(const bf16* __restrict__ Wb,
                                              const bf16* __restrict__ xT,
                                              bf16* __restrict__ qkvT,
                                              float* __restrict__ cs) {
    __shared__ __attribute__((aligned(16))) bf16 xs[64 * 72];
    __shared__ __attribute__((aligned(16))) bf16 ws2[64 * 72];
    int wid = threadIdx.x >> 6, lane = threadIdx.x & 63;
    int quad = lane >> 4, l15 = lane & 15;
    int g  = blockIdx.x % 24;
    int pb = (blockIdx.x / 24) * 64;
    int h = g / 3, sec = g % 3;          // 0=key 1=query 2=value
    int ob = g * 64;

    int srow = threadIdx.x >> 2;          // 0..63
    int scol = (threadIdx.x & 3) * 16;    // 0/16/32/48

    f32x4 acc[4];
#pragma unroll
    for (int c = 0; c < 4; c++) acc[c] = (f32x4){0.f, 0.f, 0.f, 0.f};

    bf16x8 fx0 = *(const bf16x8*)(xT + (pb + srow) * 256 + scol);
    bf16x8 fx1 = *(const bf16x8*)(xT + (pb + srow) * 256 + scol + 8);
    bf16x8 fw0 = *(const bf16x8*)(Wb + (ob + srow) * 256 + scol);
    bf16x8 fw1 = *(const bf16x8*)(Wb + (ob + srow) * 256 + scol + 8);

    for (int c4 = 0; c4 < 4; c4++) {
        __syncthreads();
        *(bf16x8*)(xs  + srow * 72 + scol)     = fx0;
        *(bf16x8*)(xs  + srow * 72 + scol + 8) = fx1;
        *(bf16x8*)(ws2 + srow * 72 + scol)     = fw0;
        *(bf16x8*)(ws2 + srow * 72 + scol + 8) = fw1;
        __syncthreads();

        if (c4 < 3) {
            int co = (c4 + 1) * 64;
            fx0 = *(const bf16x8*)(xT + (pb + srow) * 256 + co + scol);
            fx1 = *(const bf16x8*)(xT + (pb + srow) * 256 + co + scol + 8);
            fw0 = *(const bf16x8*)(Wb + (ob + srow) * 256 + co + scol);
            fw1 = *(const bf16x8*)(Wb + (ob + srow) * 256 + co + scol + 8);
        }

#pragma unroll
        for (int k2 = 0; k2 < 2; k2++) {
            bf16x8 a = *(const bf16x8*)(ws2 + (wid * 16 + l15) * 72 + k2 * 32 + quad * 8);
#pragma unroll
            for (int c = 0; c < 4; c++) {
                bf16x8 b = *(const bf16x8*)(xs + (c * 16 + l15) * 72 + k2 * 32 + quad * 8);
                acc[c] = __builtin_amdgcn_mfma_f32_16x16x32_bf16(a, b, acc[c], 0, 0, 0);
            }
        }
    }

    int ch0 = wid * 16 + quad * 4;
#pragma unroll
    for (int r = 0; r < 4; r++) {
        float sp  = acc[0][r] + acc[1][r] + acc[2][r] + acc[3][r];
        float ssp = acc[0][r] * acc[0][r] + acc[1][r] * acc[1][r]
                  + acc[2][r] * acc[2][r] + acc[3][r] * acc[3][r];
#pragma unroll
        for (int m = 1; m < 16; m <<= 1) {
            sp  += __shfl_xor(sp,  m, 64);
            ssp += __shfl_xor(ssp, m, 64);
        }
        if (l15 == 0) {
            atomicAdd(cs + (ob + ch0 + r) * 2,     sp);
            atomicAdd(cs + (ob + ch0 + r) * 2 + 1, ssp);
        }
    }

    __syncthreads();
    bf16* tile = xs;
    if (sec == 2) {                       // V: tile[kd][l], stride 72
#pragma unroll
        for (int c = 0; c < 4; c++)
#pragma unroll
            for (int r = 0; r < 4; r++)
                tile[(ch0 + r) * 72 + c * 16 + l15] = (bf16)acc[c][r];
    } else {                              // Q/K: tile[l or px][ch], stride 72
#pragma unroll
        for (int c = 0; c < 4; c++) {
            bf16x4 o;
#pragma unroll
            for (int r = 0; r < 4; r++) o[r] = (bf16)acc[c][r];
            *(bf16x4*)(&tile[(c * 16 + l15) * 72 + ch0]) = o;
        }
    }
    __syncthreads();
    bf16* base = qkvT + h * 786432;
    int t2 = pb >> 6;                     // this block covers exactly one L-tile
    if (sec == 1) {                       // Q linear [px][64]
#pragma unroll
        for (int it = 0; it < 2; it++) {
            int e = it * 256 + threadIdx.x; int px = e >> 3; int cho = (e & 7) * 8;
            *(bf16x8*)(base + (pb + px) * 64 + cho) = *(const bf16x8*)(&tile[px * 72 + cho]);
        }
    } else {                              // K/V blocked: dest offset = t*4096 + e*8
        bf16* dst = base + (sec == 0 ? 262144 : 524288);
#pragma unroll
        for (int it = 0; it < 2; it++) {
            int e = it * 256 + threadIdx.x;
            int r = (e >> 8) * 32 + (e & 31);
            int c = ((e >> 6) & 3) * 16 + ((e >> 5) & 1) * 8;
            *(bf16x8*)(dst + t2 * 4096 + e * 8) = *(const bf16x8*)(&tile[r * 72 + c]);
        }
    }
}

// ---------------- K2: in-place affine on Q (linear) / K (blocked) ----------------
__global__ __launch_bounds__(256) void k_normqk(bf16* __restrict__ qkv,
                                                const float2* __restrict__ cs,
                                                const float* __restrict__ gnw,
                                                const float* __restrict__ gnb) {
    int h    = blockIdx.x >> 8;
    int base = (blockIdx.x & 255) * 2048;
    int isQ  = base < 262144;
    int g    = h * 3 + (isQ ? 1 : 0);

    int c = threadIdx.x & 63;
    float2 v = cs[g * 64 + c];
    float s = v.x, ss = v.y;
#pragma unroll
    for (int m = 1; m < 64; m <<= 1) { s += __shfl_xor(s, m, 64); ss += __shfl_xor(ss, m, 64); }
    const float N = 262144.0f;
    float mean = s / N;
    float inv  = rsqrtf(ss / N - mean * mean + 1e-5f);
    float f = isQ ? QF : 1.0f;

    int e = base + threadIdx.x * 8;
    int gc;
    if (isQ) gc = h * 192 + 64 + (e & 63);
    else { int ek = e - 262144; gc = h * 192 + ((ek >> 9) & 3) * 16 + ((ek >> 8) & 1) * 8; }
    bf16* p = qkv + h * 786432 + e;
    bf16x8 vv = *(bf16x8*)p;
    bf16x8 o;
#pragma unroll
    for (int j = 0; j < 8; j++) {
        float gw = gnw[gc + j];
        float a = inv * gw * f;
        float b = (gnb[gc + j] - mean * inv * gw) * f;
        o[j] = (bf16)(a * (float)vv[j] + b);
    }
    *(bf16x8*)p = o;
}

// helper: one 32x32 C-block (S) -> exp2 -> two PV B-fragments (named scalars only)
#define PF_BLOCK(S, PFA, PFB)                                                   \
    {                                                                           \
        float p0 = EXPF(S[0]),  p1 = EXPF(S[1]),  p2 = EXPF(S[2]),  p3 = EXPF(S[3]);   \
        float p4 = EXPF(S[4]),  p5 = EXPF(S[5]),  p6 = EXPF(S[6]),  p7 = EXPF(S[7]);   \
        float p8 = EXPF(S[8]),  p9 = EXPF(S[9]),  p10 = EXPF(S[10]), p11 = EXPF(S[11]); \
        float p12 = EXPF(S[12]), p13 = EXPF(S[13]), p14 = EXPF(S[14]), p15 = EXPF(S[15]); \
        lacc += (((p0 + p1) + (p2 + p3)) + ((p4 + p5) + (p6 + p7)))             \
              + (((p8 + p9) + (p10 + p11)) + ((p12 + p13) + (p14 + p15)));      \
        U4 lo, hi;                                                              \
        lo.v[0] = (bf16)p0;  lo.v[1] = (bf16)p1;  lo.v[2] = (bf16)p2;  lo.v[3] = (bf16)p3;  \
        hi.v[0] = (bf16)p4;  hi.v[1] = (bf16)p5;  hi.v[2] = (bf16)p6;  hi.v[3] = (bf16)p7;  \
        unsigned sa = half ? lo.u[0] : hi.u[0];                                 \
        unsigned sb = half ? lo.u[1] : hi.u[1];                                 \
        unsigned ra = (unsigned)__shfl_xor((int)sa, 32, 64);                    \
        unsigned rb = (unsigned)__shfl_xor((int)sb, 32, 64);                    \
        U8 fA;                                                                  \
        fA.u[0] = half ? ra : lo.u[0];  fA.u[1] = half ? rb : lo.u[1];          \
        fA.u[2] = half ? hi.u[0] : ra;  fA.u[3] = half ? hi.u[1] : rb;          \
        PFA = fA.v;                                                             \
        U4 lo2, hi2;                                                            \
        lo2.v[0] = (bf16)p8;  lo2.v[1] = (bf16)p9;  lo2.v[2] = (bf16)p10; lo2.v[3] = (bf16)p11; \
        hi2.v[0] = (bf16)p12; hi2.v[1] = (bf16)p13; hi2.v[2] = (bf16)p14; hi2.v[3] = (bf16)p15; \
        unsigned sc = half ? lo2.u[0] : hi2.u[0];                               \
        unsigned sd = half ? lo2.u[1] : hi2.u[1];                               \
        unsigned rc = (unsigned)__shfl_xor((int)sc, 32, 64);                    \
        unsigned rd = (unsigned)__shfl_xor((int)sd, 32, 64);                    \
        U8 fB;                                                                  \
        fB.u[0] = half ? rc : lo2.u[0];  fB.u[1] = half ? rd : lo2.u[1];        \
        fB.u[2] = half ? hi2.u[0] : rc;  fB.u[3] = half ? hi2.u[1] : rd;        \
        PFB = fB.v;                                                             \
    }

// ---------------- K3: flash attention, zero LDS, software-pipelined frag loads ----------------
// grid 768 = 8 heads x 32 q-blocks(128q) x 3 L-splits; wave owns 32 q.
__global__ __launch_bounds__(256, 3) void k_attn(const bf16* __restrict__ qkvT,
                                                 bf16* __restrict__ Opart,
                                                 float* __restrict__ Lsum) {
    int bid   = blockIdx.x;
    int h     = bid & 7;                  // XCD L2 affinity
    int qb    = (bid >> 3) & 31;
    int split = bid >> 8;                 // 0..2
    int lane = threadIdx.x & 63;
    int wid = threadIdx.x >> 6;
    int l31 = lane & 31, half = lane >> 5;
    const bf16* QT = qkvT + h * 786432;
    const bf16* KT = QT + 262144;
    const bf16* V  = QT + 524288;
    int qw = qb * 128 + wid * 32;         // wave's 32 q
    int lofs = lane * 8;

    // Q B-fragments (normalized already): B[n=q][k=kd]
    bf16x8 bq[4];
#pragma unroll
    for (int ks = 0; ks < 4; ks++)
        bq[ks] = *(const bf16x8*)(QT + (qw + l31) * 64 + ks * 16 + half * 8);

    f32x16 oacc0 = (f32x16)(0.0f), oacc1 = (f32x16)(0.0f);   // kd 0-31, 32-63
    float ls = 0.f;

    int t0 = (split * 64) / 3, t1 = ((split + 1) * 64) / 3;

    // preload tile t0's K fragments
    bf16x8 kf[8];
#pragma unroll
    for (int i = 0; i < 8; i++) kf[i] = *(const bf16x8*)(KT + t0 * 4096 + lofs + i * 512);

    for (int t = t0; t < t1; t++) {
        // S^T = K·Q (consumes kf, loaded one full tile ago -> latency hidden)
        f32x16 s0 = (f32x16)(0.0f), s1 = (f32x16)(0.0f);
#pragma unroll
        for (int ks = 0; ks < 4; ks++) {
            s0 = __builtin_amdgcn_mfma_f32_32x32x16_bf16(kf[ks],     bq[ks], s0, 0, 0, 0);
            s1 = __builtin_amdgcn_mfma_f32_32x32x16_bf16(kf[4 + ks], bq[ks], s1, 0, 0, 0);
        }

        // V frags for THIS tile: consumed after the exp2/pack stretch below
        bf16x8 vf[8];
        const bf16* Vt = V + t * 4096 + lofs;
#pragma unroll
        for (int i = 0; i < 8; i++) vf[i] = *(const bf16x8*)(Vt + i * 512);

        // K frags for NEXT tile into the same registers (consumed next iteration)
        if (t + 1 < t1) {
            const bf16* Kn = KT + (t + 1) * 4096 + lofs;
#pragma unroll
            for (int i = 0; i < 8; i++) kf[i] = *(const bf16x8*)(Kn + i * 512);
        }

        float lacc = ls;
        bf16x8 pf0, pf1, pf2, pf3;
        PF_BLOCK(s0, pf0, pf1);           // l 0..31
        PF_BLOCK(s1, pf2, pf3);           // l 32..63
        ls = lacc;

        // O[kd][q] += V·P  (vf[kb*4+ks] pairs with pf[ks])
        oacc0 = __builtin_amdgcn_mfma_f32_32x32x16_bf16(vf[0], pf0, oacc0, 0, 0, 0);
        oacc1 = __builtin_amdgcn_mfma_f32_32x32x16_bf16(vf[4], pf0, oacc1, 0, 0, 0);
        oacc0 = __builtin_amdgcn_mfma_f32_32x32x16_bf16(vf[1], pf1, oacc0, 0, 0, 0);
        oacc1 = __builtin_amdgcn_mfma_f32_32x32x16_bf16(vf[5], pf1, oacc1, 0, 0, 0);
        oacc0 = __builtin_amdgcn_mfma_f32_32x32x16_bf16(vf[2], pf2, oacc0, 0, 0, 0);
        oacc1 = __builtin_amdgcn_mfma_f32_32x32x16_bf16(vf[6], pf2, oacc1, 0, 0, 0);
        oacc0 = __builtin_amdgcn_mfma_f32_32x32x16_bf16(vf[3], pf3, oacc0, 0, 0, 0);
        oacc1 = __builtin_amdgcn_mfma_f32_32x32x16_bf16(vf[7], pf3, oacc1, 0, 0, 0);

        // pacing barrier (no LDS -> no drain semantics): keeps the WG's waves
        // on the same tile so L1 serves the shared K/V re-reads
        __builtin_amdgcn_s_barrier();
    }

    // denominator: halves hold complementary l-rows of col q
    ls += __shfl_xor(ls, 32, 64);
    if (half == 0)
        Lsum[split * 32768 + h * 4096 + qw + l31] = ls;

    // partial O (unnormalized, bf16): row = h*64+kd, col = q
    bf16* Ob = Opart + split * 2097152;
#pragma unroll
    for (int r = 0; r < 16; r++) {
        int kd = (r & 3) + 8 * (r >> 2) + 4 * half;
        Ob[(h * 64 + kd) * 4096 + qw + l31]        = (bf16)oacc0[r];
        Ob[(h * 64 + 32 + kd) * 4096 + qw + l31]   = (bf16)oacc1[r];
    }
}

// ---------------- K4: combine 3 splits + V affine (stats inline) + normalize ----------------
__global__ void k_final(const bf16* __restrict__ Opart, const float* __restrict__ Lsum,
                        const float2* __restrict__ cs, const float* __restrict__ gnw,
                        const float* __restrict__ gnb, float* __restrict__ out) {
    int gid = blockIdx.x * 256 + threadIdx.x;    // 262144
    int row = gid >> 9;
    int c8  = (gid & 511) << 3;
    int h   = row >> 6;

    int g = h * 3 + 2;
    int c = threadIdx.x & 63;
    float2 v = cs[g * 64 + c];
    float s = v.x, ss = v.y;
#pragma unroll
    for (int m = 1; m < 64; m <<= 1) { s += __shfl_xor(s, m, 64); ss += __shfl_xor(ss, m, 64); }
    const float N = 262144.0f;
    float mean = s / N;
    float inv  = rsqrtf(ss / N - mean * mean + 1e-5f);
    int gi = h * 192 + 128 + (row & 63);
    float gw = gnw[gi];
    float va = inv * gw;
    float vb = gnb[gi] - mean * inv * gw;

    float o[8] = {0, 0, 0, 0, 0, 0, 0, 0};
    float l[8] = {0, 0, 0, 0, 0, 0, 0, 0};
#pragma unroll
    for (int sp = 0; sp < 3; sp++) {
        bf16x8 vv = *(const bf16x8*)(Opart + sp * 2097152 + row * 4096 + c8);
        const float* L = Lsum + sp * 32768 + h * 4096 + c8;
        float4 l0 = *(const float4*)L;
        float4 l1 = *(const float4*)(L + 4);
#pragma unroll
        for (int j = 0; j < 8; j++) o[j] += (float)vv[j];
        l[0] += l0.x; l[1] += l0.y; l[2] += l0.z; l[3] += l0.w;
        l[4] += l1.x; l[5] += l1.y; l[6] += l1.z; l[7] += l1.w;
    }
    float4 r0, r1;
    r0.x = va * o[0] / l[0] + vb; r0.y = va * o[1] / l[1] + vb;
    r0.z = va * o[2] / l[2] + vb; r0.w = va * o[3] / l[3] + vb;
    r1.x = va * o[4] / l[4] + vb; r1.y = va * o[5] / l[5] + vb;
    r1.z = va * o[6] / l[6] + vb; r1.w = va * o[7] / l[7] + vb;
    *(float4*)(out + row * 4096 + c8)     = r0;
    *(float4*)(out + row * 4096 + c8 + 4) = r1;
}

extern "C" void kernel_launch(void* const* d_in, const int* in_sizes, int n_in,
                              void* d_out, int out_size, void* d_ws, size_t ws_size,
                              hipStream_t stream) {
    const float* x      = (const float*)d_in[0];
    const float* conv_w = (const float*)d_in[1];
    const float* gn_w   = (const float*)d_in[2];
    const float* gn_b   = (const float*)d_in[3];
    float* out = (float*)d_out;
    char* ws = (char*)d_ws;

    // qkvT [0,12582912); Opart 3x4MB [12582912,25165824); Wb/xT alias Opart
    // (dead after k_conv; Opart first written by k_attn).
    bf16*   qkvT  = (bf16*) (ws);
    bf16*   Opart = (bf16*) (ws + 12582912);
    bf16*   Wb    = (bf16*) (ws + 12582912);
    bf16*   xT    = (bf16*) (ws + 13369344);
    float*  Lsum  = (float*)(ws + 25165824);        // 3*131072 B
    float*  cs    = (float*)(ws + 25559040);        // 12288 B

    hipLaunchKernelGGL(k_misc,   dim3(897),  dim3(256), 0, stream, x, conv_w, xT, Wb, cs);
    hipLaunchKernelGGL(k_conv,   dim3(1536), dim3(256), 0, stream, Wb, xT, qkvT, cs);
    hipLaunchKernelGGL(k_normqk, dim3(2048), dim3(256), 0, stream, qkvT, (const float2*)cs, gn_w, gn_b);
    hipLaunchKernelGGL(k_attn,   dim3(768),  dim3(256), 0, stream, qkvT, Opart, Lsum);
    hipLaunchKernelGGL(k_final,  dim3(1024), dim3(256), 0, stream, Opart, Lsum, (const float2*)cs, gn_w, gn_b, out);
}

// Round 14
// 140.568 us; speedup vs baseline: 1.0095x; 1.0038x over previous
//
#include <hip/hip_runtime.h>

typedef __bf16 bf16;
typedef __bf16 bf16x8 __attribute__((ext_vector_type(8)));
typedef __bf16 bf16x4 __attribute__((ext_vector_type(4)));
typedef float f32x4 __attribute__((ext_vector_type(4)));
typedef float f32x16 __attribute__((ext_vector_type(16)));

// x: [256][4096] f32, conv_w: [1536][256] f32, out: [512][4096] f32
// heads=8; channels per head: key [0:64), query [64:128), value [128:192)
// qkvT per head (786432): [QT(query) [4096][64] | KT(key) [4096][64] | V [64][4096]]
// k_conv stores RAW bf16. k_attn applies Q/K GroupNorm affine inline (Q at frag
// load with log2(e)/8 folded; K at LDS staging; stats reduced from cs in-kernel).
// V affine folds into k_final: out = a_v*(sum O)/(sum L) + b_v.

#define QF 0.18033688011112042f   // log2(e)/8
#define EXPF(x) __builtin_amdgcn_exp2f(x)

union U4 { bf16x4 v; unsigned u[2]; };
union U8 { bf16x8 v; unsigned u[4]; };

// ---------------- K_misc: xpose + cast_w ----------------
__global__ void k_misc(const float* __restrict__ x, const float* __restrict__ w,
                       bf16* __restrict__ xT, bf16* __restrict__ wb) {
    int b = blockIdx.x;
    if (b < 512) {
        int t = b * 256 + threadIdx.x;
        int p  = t & 4095;
        int c0 = (t >> 12) * 8;
        bf16x8 o;
#pragma unroll
        for (int j = 0; j < 8; j++) o[j] = (bf16)x[(c0 + j) * 4096 + p];
        *(bf16x8*)(xT + p * 256 + c0) = o;
    } else {
        int idx = ((b - 512) * 256 + threadIdx.x) * 4;
        float4 f = *(const float4*)(w + idx);
        bf16x4 o;
        o[0] = (bf16)f.x; o[1] = (bf16)f.y; o[2] = (bf16)f.z; o[3] = (bf16)f.w;
        *(bf16x4*)(wb + idx) = o;
    }
}

// ---------------- K1: conv GEMM, LDS-staged fragments (R10 proven) ----------------
__global__ __launch_bounds__(256) void k_conv(const bf16* __restrict__ Wb,
                                              const bf16* __restrict__ xT,
                                              bf16* __restrict__ qkvT,
                                              float* __restrict__ cs) {
    __shared__ __attribute__((aligned(16))) bf16 xs[64 * 72];
    __shared__ __attribute__((aligned(16))) bf16 ws2[64 * 72];
    int wid = threadIdx.x >> 6, lane = threadIdx.x & 63;
    int quad = lane >> 4, l15 = lane & 15;
    int g  = blockIdx.x % 24;
    int pb = (blockIdx.x / 24) * 64;
    int h = g / 3, sec = g % 3;          // 0=key 1=query 2=value
    int ob = g * 64;

    int srow = threadIdx.x >> 2;          // 0..63
    int scol = (threadIdx.x & 3) * 16;    // 0/16/32/48

    f32x4 acc[4];
#pragma unroll
    for (int c = 0; c < 4; c++) acc[c] = (f32x4){0.f, 0.f, 0.f, 0.f};

    bf16x8 fx0 = *(const bf16x8*)(xT + (pb + srow) * 256 + scol);
    bf16x8 fx1 = *(const bf16x8*)(xT + (pb + srow) * 256 + scol + 8);
    bf16x8 fw0 = *(const bf16x8*)(Wb + (ob + srow) * 256 + scol);
    bf16x8 fw1 = *(const bf16x8*)(Wb + (ob + srow) * 256 + scol + 8);

    for (int c4 = 0; c4 < 4; c4++) {
        __syncthreads();
        *(bf16x8*)(xs  + srow * 72 + scol)     = fx0;
        *(bf16x8*)(xs  + srow * 72 + scol + 8) = fx1;
        *(bf16x8*)(ws2 + srow * 72 + scol)     = fw0;
        *(bf16x8*)(ws2 + srow * 72 + scol + 8) = fw1;
        __syncthreads();

        if (c4 < 3) {
            int co = (c4 + 1) * 64;
            fx0 = *(const bf16x8*)(xT + (pb + srow) * 256 + co + scol);
            fx1 = *(const bf16x8*)(xT + (pb + srow) * 256 + co + scol + 8);
            fw0 = *(const bf16x8*)(Wb + (ob + srow) * 256 + co + scol);
            fw1 = *(const bf16x8*)(Wb + (ob + srow) * 256 + co + scol + 8);
        }

#pragma unroll
        for (int k2 = 0; k2 < 2; k2++) {
            bf16x8 a = *(const bf16x8*)(ws2 + (wid * 16 + l15) * 72 + k2 * 32 + quad * 8);
#pragma unroll
            for (int c = 0; c < 4; c++) {
                bf16x8 b = *(const bf16x8*)(xs + (c * 16 + l15) * 72 + k2 * 32 + quad * 8);
                acc[c] = __builtin_amdgcn_mfma_f32_16x16x32_bf16(a, b, acc[c], 0, 0, 0);
            }
        }
    }

    int ch0 = wid * 16 + quad * 4;
#pragma unroll
    for (int r = 0; r < 4; r++) {
        float sp  = acc[0][r] + acc[1][r] + acc[2][r] + acc[3][r];
        float ssp = acc[0][r] * acc[0][r] + acc[1][r] * acc[1][r]
                  + acc[2][r] * acc[2][r] + acc[3][r] * acc[3][r];
#pragma unroll
        for (int m = 1; m < 16; m <<= 1) {
            sp  += __shfl_xor(sp,  m, 64);
            ssp += __shfl_xor(ssp, m, 64);
        }
        if (l15 == 0) {
            atomicAdd(cs + (ob + ch0 + r) * 2,     sp);
            atomicAdd(cs + (ob + ch0 + r) * 2 + 1, ssp);
        }
    }

    __syncthreads();
    bf16* tile = xs;
    if (sec == 2) {                       // V wants [ch][px]
#pragma unroll
        for (int c = 0; c < 4; c++)
#pragma unroll
            for (int r = 0; r < 4; r++)
                tile[(ch0 + r) * 72 + c * 16 + l15] = (bf16)acc[c][r];
    } else {                              // Q/K want [px][ch]
#pragma unroll
        for (int c = 0; c < 4; c++) {
            bf16x4 o;
#pragma unroll
            for (int r = 0; r < 4; r++) o[r] = (bf16)acc[c][r];
            *(bf16x4*)(&tile[(c * 16 + l15) * 72 + ch0]) = o;
        }
    }
    __syncthreads();
    bf16* base = qkvT + h * 786432;
    int t = threadIdx.x;
    if (sec == 2) {
        bf16* V = base + 524288;
#pragma unroll
        for (int it = 0; it < 2; it++) {
            int e = it * 256 + t; int ch = e >> 3; int pxo = (e & 7) * 8;
            *(bf16x8*)(V + ch * 4096 + pb + pxo) = *(const bf16x8*)(&tile[ch * 72 + pxo]);
        }
    } else {
        bf16* dst = base + (sec == 0 ? 262144 : 0);
#pragma unroll
        for (int it = 0; it < 2; it++) {
            int e = it * 256 + t; int px = e >> 3; int cho = (e & 7) * 8;
            *(bf16x8*)(dst + (pb + px) * 64 + cho) = *(const bf16x8*)(&tile[px * 72 + cho]);
        }
    }
}

// helper: one 32x32 C-block (S) -> exp2 -> two PV B-fragments (named scalars only)
#define PF_BLOCK(S, PFA, PFB)                                                   \
    {                                                                           \
        float p0 = EXPF(S[0]),  p1 = EXPF(S[1]),  p2 = EXPF(S[2]),  p3 = EXPF(S[3]);   \
        float p4 = EXPF(S[4]),  p5 = EXPF(S[5]),  p6 = EXPF(S[6]),  p7 = EXPF(S[7]);   \
        float p8 = EXPF(S[8]),  p9 = EXPF(S[9]),  p10 = EXPF(S[10]), p11 = EXPF(S[11]); \
        float p12 = EXPF(S[12]), p13 = EXPF(S[13]), p14 = EXPF(S[14]), p15 = EXPF(S[15]); \
        lacc += (((p0 + p1) + (p2 + p3)) + ((p4 + p5) + (p6 + p7)))             \
              + (((p8 + p9) + (p10 + p11)) + ((p12 + p13) + (p14 + p15)));      \
        U4 lo, hi;                                                              \
        lo.v[0] = (bf16)p0;  lo.v[1] = (bf16)p1;  lo.v[2] = (bf16)p2;  lo.v[3] = (bf16)p3;  \
        hi.v[0] = (bf16)p4;  hi.v[1] = (bf16)p5;  hi.v[2] = (bf16)p6;  hi.v[3] = (bf16)p7;  \
        unsigned sa = half ? lo.u[0] : hi.u[0];                                 \
        unsigned sb = half ? lo.u[1] : hi.u[1];                                 \
        unsigned ra = (unsigned)__shfl_xor((int)sa, 32, 64);                    \
        unsigned rb = (unsigned)__shfl_xor((int)sb, 32, 64);                    \
        U8 fA;                                                                  \
        fA.u[0] = half ? ra : lo.u[0];  fA.u[1] = half ? rb : lo.u[1];          \
        fA.u[2] = half ? hi.u[0] : ra;  fA.u[3] = half ? hi.u[1] : rb;          \
        PFA = fA.v;                                                             \
        U4 lo2, hi2;                                                            \
        lo2.v[0] = (bf16)p8;  lo2.v[1] = (bf16)p9;  lo2.v[2] = (bf16)p10; lo2.v[3] = (bf16)p11; \
        hi2.v[0] = (bf16)p12; hi2.v[1] = (bf16)p13; hi2.v[2] = (bf16)p14; hi2.v[3] = (bf16)p15; \
        unsigned sc = half ? lo2.u[0] : hi2.u[0];                               \
        unsigned sd = half ? lo2.u[1] : hi2.u[1];                               \
        unsigned rc = (unsigned)__shfl_xor((int)sc, 32, 64);                    \
        unsigned rd = (unsigned)__shfl_xor((int)sd, 32, 64);                    \
        U8 fB;                                                                  \
        fB.u[0] = half ? rc : lo2.u[0];  fB.u[1] = half ? rd : lo2.u[1];        \
        fB.u[2] = half ? hi2.u[0] : rc;  fB.u[3] = half ? hi2.u[1] : rd;        \
        PFB = fB.v;                                                             \
    }

// ---------------- K2: flash attention, R9 skeleton + fused Q/K affine ----------------
// grid 768 = 8 heads x 32 q-blocks(128q) x 3 L-splits; wave owns 32 q.
__global__ __launch_bounds__(256, 3) void k_attn(const bf16* __restrict__ qkvT,
                                                 const float2* __restrict__ cs,
                                                 const float* __restrict__ gnw,
                                                 const float* __restrict__ gnb,
                                                 bf16* __restrict__ Opart,
                                                 float* __restrict__ Lsum) {
    int bid   = blockIdx.x;
    int h     = bid & 7;                  // XCD L2 affinity
    int qb    = (bid >> 3) & 31;
    int split = bid >> 8;                 // 0..2
    int wid = threadIdx.x >> 6, lane = threadIdx.x & 63;
    int l31 = lane & 31, half = lane >> 5;
    const bf16* QT = qkvT + h * 786432;
    const bf16* KT = QT + 262144;
    const bf16* V  = QT + 524288;
    int qw = qb * 128 + wid * 32;         // wave's 32 q

    __shared__ __attribute__((aligned(16))) bf16 Ks[64 * 72];
    __shared__ __attribute__((aligned(16))) bf16 Vs[64 * 72];

    int r0   = threadIdx.x >> 3;          // staging rows r0 and r0+32
    int koff = (threadIdx.x & 7) * 8;

    // ---- inline group stats for Q (g=h*3+1) and K (g=h*3+0) ----
    float2 vq = cs[(h * 3 + 1) * 64 + lane];
    float2 vk = cs[(h * 3 + 0) * 64 + lane];
    float sq = vq.x, ssq = vq.y, sk = vk.x, ssk = vk.y;
#pragma unroll
    for (int m = 1; m < 64; m <<= 1) {
        sq += __shfl_xor(sq, m, 64); ssq += __shfl_xor(ssq, m, 64);
        sk += __shfl_xor(sk, m, 64); ssk += __shfl_xor(ssk, m, 64);
    }
    const float N = 262144.0f;
    float mq = sq / N, iq = rsqrtf(ssq / N - mq * mq + 1e-5f);
    float mk = sk / N, ik = rsqrtf(ssk / N - mk * mk + 1e-5f);

    // ---- staging-channel K affine consts (lane always stages kd in [koff,koff+8)) ----
    float akc[8], bkc[8];
#pragma unroll
    for (int j = 0; j < 8; j++) {
        float gw = gnw[h * 192 + koff + j];
        akc[j] = ik * gw;
        bkc[j] = gnb[h * 192 + koff + j] - mk * akc[j];
    }

    // ---- Q B-fragments with affine (loop-invariant): B[n=q][k=kd] ----
    bf16x8 bq[4];
#pragma unroll
    for (int ks = 0; ks < 4; ks++) {
        bf16x8 raw = *(const bf16x8*)(QT + (qw + l31) * 64 + ks * 16 + half * 8);
        bf16x8 o;
#pragma unroll
        for (int j = 0; j < 8; j++) {
            int ch = h * 192 + 64 + ks * 16 + half * 8 + j;
            float gw = gnw[ch];
            float a = iq * gw * QF;
            float b = (gnb[ch] - mq * iq * gw) * QF;
            o[j] = (bf16)(a * (float)raw[j] + b);
        }
        bq[ks] = o;
    }

    f32x16 oacc0 = (f32x16)(0.0f), oacc1 = (f32x16)(0.0f);   // kd 0-31, 32-63
    float ls = 0.f;

    int t0 = (split * 64) / 3, t1 = ((split + 1) * 64) / 3;

    bf16x8 kf0, kf1, vf0, vf1;            // register prefetch
    {
        int lb0 = t0 * 64;
        kf0 = *(const bf16x8*)(KT + (lb0 + r0) * 64 + koff);
        kf1 = *(const bf16x8*)(KT + (lb0 + r0 + 32) * 64 + koff);
        vf0 = *(const bf16x8*)(V + r0 * 4096 + lb0 + koff);
        vf1 = *(const bf16x8*)(V + (r0 + 32) * 4096 + lb0 + koff);
    }

    for (int lt = t0; lt < t1; lt++) {
        __syncthreads();
        {
            bf16x8 k0, k1;
#pragma unroll
            for (int j = 0; j < 8; j++) {
                k0[j] = (bf16)(akc[j] * (float)kf0[j] + bkc[j]);
                k1[j] = (bf16)(akc[j] * (float)kf1[j] + bkc[j]);
            }
            *(bf16x8*)(Ks + r0 * 72 + koff)        = k0;
            *(bf16x8*)(Ks + (r0 + 32) * 72 + koff) = k1;
            *(bf16x8*)(Vs + r0 * 72 + koff)        = vf0;
            *(bf16x8*)(Vs + (r0 + 32) * 72 + koff) = vf1;
        }
        __syncthreads();

        if (lt + 1 < t1) {
            int nb = (lt + 1) * 64;
            kf0 = *(const bf16x8*)(KT + (nb + r0) * 64 + koff);
            kf1 = *(const bf16x8*)(KT + (nb + r0 + 32) * 64 + koff);
            vf0 = *(const bf16x8*)(V + r0 * 4096 + nb + koff);
            vf1 = *(const bf16x8*)(V + (r0 + 32) * 4096 + nb + koff);
        }

        // S^T = K·Q : two 32x32 C-tiles (l 0-31, 32-63), col q = lane&31
        f32x16 s0 = (f32x16)(0.0f), s1 = (f32x16)(0.0f);
#pragma unroll
        for (int ks = 0; ks < 4; ks++) {
            s0 = __builtin_amdgcn_mfma_f32_32x32x16_bf16(
                *(const bf16x8*)(Ks + l31 * 72 + ks * 16 + half * 8), bq[ks], s0, 0, 0, 0);
            s1 = __builtin_amdgcn_mfma_f32_32x32x16_bf16(
                *(const bf16x8*)(Ks + (32 + l31) * 72 + ks * 16 + half * 8), bq[ks], s1, 0, 0, 0);
        }

        float lacc = ls;
        bf16x8 pf0, pf1, pf2, pf3;
        PF_BLOCK(s0, pf0, pf1);           // l 0..31
        PF_BLOCK(s1, pf2, pf3);           // l 32..63
        ls = lacc;

        // O[kd][q] += V·P ; V A-frags read per-use from LDS
        oacc0 = __builtin_amdgcn_mfma_f32_32x32x16_bf16(
            *(const bf16x8*)(Vs + l31 * 72 +  0 + half * 8), pf0, oacc0, 0, 0, 0);
        oacc1 = __builtin_amdgcn_mfma_f32_32x32x16_bf16(
            *(const bf16x8*)(Vs + (32 + l31) * 72 +  0 + half * 8), pf0, oacc1, 0, 0, 0);
        oacc0 = __builtin_amdgcn_mfma_f32_32x32x16_bf16(
            *(const bf16x8*)(Vs + l31 * 72 + 16 + half * 8), pf1, oacc0, 0, 0, 0);
        oacc1 = __builtin_amdgcn_mfma_f32_32x32x16_bf16(
            *(const bf16x8*)(Vs + (32 + l31) * 72 + 16 + half * 8), pf1, oacc1, 0, 0, 0);
        oacc0 = __builtin_amdgcn_mfma_f32_32x32x16_bf16(
            *(const bf16x8*)(Vs + l31 * 72 + 32 + half * 8), pf2, oacc0, 0, 0, 0);
        oacc1 = __builtin_amdgcn_mfma_f32_32x32x16_bf16(
            *(const bf16x8*)(Vs + (32 + l31) * 72 + 32 + half * 8), pf2, oacc1, 0, 0, 0);
        oacc0 = __builtin_amdgcn_mfma_f32_32x32x16_bf16(
            *(const bf16x8*)(Vs + l31 * 72 + 48 + half * 8), pf3, oacc0, 0, 0, 0);
        oacc1 = __builtin_amdgcn_mfma_f32_32x32x16_bf16(
            *(const bf16x8*)(Vs + (32 + l31) * 72 + 48 + half * 8), pf3, oacc1, 0, 0, 0);
    }

    // denominator: halves hold complementary l-rows of col q
    ls += __shfl_xor(ls, 32, 64);
    if (half == 0)
        Lsum[split * 32768 + h * 4096 + qw + l31] = ls;

    // partial O (unnormalized, bf16): row = h*64+kd, col = q
    bf16* Ob = Opart + split * 2097152;
#pragma unroll
    for (int r = 0; r < 16; r++) {
        int kd = (r & 3) + 8 * (r >> 2) + 4 * half;
        Ob[(h * 64 + kd) * 4096 + qw + l31]        = (bf16)oacc0[r];
        Ob[(h * 64 + 32 + kd) * 4096 + qw + l31]   = (bf16)oacc1[r];
    }
}

// ---------------- K3: combine 3 splits + V affine (stats inline) + normalize ----------------
__global__ void k_final(const bf16* __restrict__ Opart, const float* __restrict__ Lsum,
                        const float2* __restrict__ cs, const float* __restrict__ gnw,
                        const float* __restrict__ gnb, float* __restrict__ out) {
    int gid = blockIdx.x * 256 + threadIdx.x;    // 262144
    int row = gid >> 9;
    int c8  = (gid & 511) << 3;
    int h   = row >> 6;

    int g = h * 3 + 2;
    int c = threadIdx.x & 63;
    float2 v = cs[g * 64 + c];
    float s = v.x, ss = v.y;
#pragma unroll
    for (int m = 1; m < 64; m <<= 1) { s += __shfl_xor(s, m, 64); ss += __shfl_xor(ss, m, 64); }
    const float N = 262144.0f;
    float mean = s / N;
    float inv  = rsqrtf(ss / N - mean * mean + 1e-5f);
    int gi = h * 192 + 128 + (row & 63);
    float gw = gnw[gi];
    float va = inv * gw;
    float vb = gnb[gi] - mean * inv * gw;

    float o[8] = {0, 0, 0, 0, 0, 0, 0, 0};
    float l[8] = {0, 0, 0, 0, 0, 0, 0, 0};
#pragma unroll
    for (int sp = 0; sp < 3; sp++) {
        bf16x8 vv = *(const bf16x8*)(Opart + sp * 2097152 + row * 4096 + c8);
        const float* L = Lsum + sp * 32768 + h * 4096 + c8;
        float4 l0 = *(const float4*)L;
        float4 l1 = *(const float4*)(L + 4);
#pragma unroll
        for (int j = 0; j < 8; j++) o[j] += (float)vv[j];
        l[0] += l0.x; l[1] += l0.y; l[2] += l0.z; l[3] += l0.w;
        l[4] += l1.x; l[5] += l1.y; l[6] += l1.z; l[7] += l1.w;
    }
    float4 r0, r1;
    r0.x = va * o[0] / l[0] + vb; r0.y = va * o[1] / l[1] + vb;
    r0.z = va * o[2] / l[2] + vb; r0.w = va * o[3] / l[3] + vb;
    r1.x = va * o[4] / l[4] + vb; r1.y = va * o[5] / l[5] + vb;
    r1.z = va * o[6] / l[6] + vb; r1.w = va * o[7] / l[7] + vb;
    *(float4*)(out + row * 4096 + c8)     = r0;
    *(float4*)(out + row * 4096 + c8 + 4) = r1;
}

extern "C" void kernel_launch(void* const* d_in, const int* in_sizes, int n_in,
                              void* d_out, int out_size, void* d_ws, size_t ws_size,
                              hipStream_t stream) {
    const float* x      = (const float*)d_in[0];
    const float* conv_w = (const float*)d_in[1];
    const float* gn_w   = (const float*)d_in[2];
    const float* gn_b   = (const float*)d_in[3];
    float* out = (float*)d_out;
    char* ws = (char*)d_ws;

    // qkvT [0,12582912); Opart 3x4MB [12582912,25165824); Wb/xT alias Opart
    // (dead after k_conv; Opart first written by k_attn).
    bf16*   qkvT  = (bf16*) (ws);
    bf16*   Opart = (bf16*) (ws + 12582912);
    bf16*   Wb    = (bf16*) (ws + 12582912);
    bf16*   xT    = (bf16*) (ws + 13369344);
    float*  Lsum  = (float*)(ws + 25165824);        // 3*131072 B
    float*  cs    = (float*)(ws + 25559040);        // 12288 B

    hipMemsetAsync(cs, 0, 12288, stream);
    hipLaunchKernelGGL(k_misc,  dim3(896),  dim3(256), 0, stream, x, conv_w, xT, Wb);
    hipLaunchKernelGGL(k_conv,  dim3(1536), dim3(256), 0, stream, Wb, xT, qkvT, cs);
    hipLaunchKernelGGL(k_attn,  dim3(768),  dim3(256), 0, stream, qkvT, (const float2*)cs, gn_w, gn_b, Opart, Lsum);
    hipLaunchKernelGGL(k_final, dim3(1024), dim3(256), 0, stream, Opart, Lsum, (const float2*)cs, gn_w, gn_b, out);
}